// Round 10
// baseline (34.719 us; speedup 1.0000x reference)
//
#include <hip/hip_runtime.h>
#include <hip/hip_bf16.h>
#include <math.h>

// DDRFMixer: out[b,t,d] = sum_n softmax_n(x[b,t,:]·W[n,:]) * x[b,t-off_n,d]
// x: [B,T,D] fp32, W: [7,D] fp32, out: [B,T,D] fp32
// B=4, T=4096, D=1024, offsets = {1,2,4,8,16,32,64}
//
// R9 = R8 (34.4 us) + ALL-UPFRONT tap loads:
//  - All 32 VMEM loads per row (4 xv + 28 taps) issue in one batch BEFORE
//    the dot/reduce/softmax chain; taps ordered by k-chunk so consumption
//    order matches issue order (progressive vmcnt waits, single latency
//    exposure window instead of four).
//  - Costs ~112 extra VGPRs (tap[7][4] live across the reduce) -> ~3
//    waves/SIMD; each wave now hides ~4x more latency, and TLP structure
//    (one row per wave, 16384 independent waves) is unchanged.
// Kept from R8: DPP wave reduce (VALU pipe, off the LDS pipe), W staged in
// LDS once per block, 8 rows/512-thread block, clamp+mask causality,
// no-max softmax, XCD-bijective swizzle, plain float4 stores.

#define N_TAPS 7
#define DIM 1024
#define T_LEN 4096
#define BLOCK_THREADS 512
#define ROWS_PER_BLOCK 8

// ---- DPP helpers: canonical GCN wave64 sum ----
template <int CTRL>
__device__ __forceinline__ float dpp_mov0(float v) {
    return __builtin_bit_cast(float,
        __builtin_amdgcn_update_dpp(0, __builtin_bit_cast(int, v),
                                    CTRL, 0xf, 0xf, true));
}
__device__ __forceinline__ float wave_sum_bcast(float v) {
    v += dpp_mov0<0x111>(v);   // row_shr:1
    v += dpp_mov0<0x112>(v);   // row_shr:2
    v += dpp_mov0<0x114>(v);   // row_shr:4
    v += dpp_mov0<0x118>(v);   // row_shr:8   -> lane15 of each row16 = row sum
    v += dpp_mov0<0x142>(v);   // row_bcast:15 -> lane31/63 = half sums
    v += dpp_mov0<0x143>(v);   // row_bcast:31 -> lane63 = total
    return __builtin_bit_cast(float,
        __builtin_amdgcn_readlane(__builtin_bit_cast(int, v), 63));
}

__global__ __launch_bounds__(BLOCK_THREADS) void ddrf_mixer_kernel(
    const float* __restrict__ x,   // [B*T, D]
    const float* __restrict__ W,   // [N_TAPS, D]
    float* __restrict__ out,       // [B*T, D]
    int n_rows)
{
    constexpr int offs[N_TAPS] = {1, 2, 4, 8, 16, 32, 64};

    __shared__ float wlds[N_TAPS * DIM];   // 28 KB

    // ---- stage W into LDS (once per block) ----
    for (int i = threadIdx.x; i < N_TAPS * (DIM / 4); i += BLOCK_THREADS) {
        reinterpret_cast<float4*>(wlds)[i] =
            reinterpret_cast<const float4*>(W)[i];
    }
    __syncthreads();

    // ---- bijective XCD swizzle (gridDim.x = 2048, % 8 == 0) ----
    const int per = gridDim.x >> 3;
    const int wg  = (blockIdx.x & 7) * per + (blockIdx.x >> 3);

    const int wave = threadIdx.x >> 6;
    const int lane = threadIdx.x & 63;
    const int dofs = lane * 4;               // lane's base within each 256-chunk

    const int row = wg * ROWS_PER_BLOCK + wave;   // one wave per row
    if (row >= n_rows) return;
    const int t = row & (T_LEN - 1);
    const float* xrow = x + (size_t)row * DIM;

    // ---- causal clamp + mask (branch-free) ----
    const float* trow[N_TAPS];
    float tmask[N_TAPS];
#pragma unroll
    for (int n = 0; n < N_TAPS; ++n) {
        const bool ok = (t >= offs[n]);
        trow[n]  = xrow - (size_t)(ok ? offs[n] : 0) * DIM;
        tmask[n] = ok ? 1.0f : 0.0f;
    }

    // ---- issue ALL loads upfront, in consumption order ----
    // xv first (dots consume it immediately), then taps grouped by k-chunk
    // (combine consumes k=0 first ... k=3 last) -> progressive vmcnt drain.
    float4 xv[4];
#pragma unroll
    for (int k = 0; k < 4; ++k)
        xv[k] = *reinterpret_cast<const float4*>(xrow + k * 256 + dofs);

    float4 tap[4][N_TAPS];                   // [k][n], 112 VGPRs
#pragma unroll
    for (int k = 0; k < 4; ++k)
#pragma unroll
        for (int n = 0; n < N_TAPS; ++n)
            tap[k][n] = *reinterpret_cast<const float4*>(
                trow[n] + k * 256 + dofs);

    // ---- Phase 1: partial dots vs W (LDS pipe; overlaps tap latency) ----
    float p[N_TAPS];
#pragma unroll
    for (int n = 0; n < N_TAPS; ++n) {
        const float* wrow = &wlds[n * DIM];
        float4 w0 = *reinterpret_cast<const float4*>(wrow + 0 * 256 + dofs);
        float4 w1 = *reinterpret_cast<const float4*>(wrow + 1 * 256 + dofs);
        float4 w2 = *reinterpret_cast<const float4*>(wrow + 2 * 256 + dofs);
        float4 w3 = *reinterpret_cast<const float4*>(wrow + 3 * 256 + dofs);
        float s0 = fmaf(xv[0].x, w0.x, fmaf(xv[0].y, w0.y, fmaf(xv[0].z, w0.z, xv[0].w * w0.w)));
        float s1 = fmaf(xv[1].x, w1.x, fmaf(xv[1].y, w1.y, fmaf(xv[1].z, w1.z, xv[1].w * w1.w)));
        float s2 = fmaf(xv[2].x, w2.x, fmaf(xv[2].y, w2.y, fmaf(xv[2].z, w2.z, xv[2].w * w2.w)));
        float s3 = fmaf(xv[3].x, w3.x, fmaf(xv[3].y, w3.y, fmaf(xv[3].z, w3.z, xv[3].w * w3.w)));
        p[n] = (s0 + s1) + (s2 + s3);
    }

    // ---- DPP wave reduce (VALU pipe; 7 independent chains) ----
#pragma unroll
    for (int n = 0; n < N_TAPS; ++n)
        p[n] = wave_sum_bcast(p[n]);

    // ---- softmax over 7 taps (no max subtraction; logits small) + mask ----
    float wn[N_TAPS];
    float wsum = 0.f;
#pragma unroll
    for (int n = 0; n < N_TAPS; ++n) {
        wn[n] = __expf(p[n]);
        wsum += wn[n];
    }
    const float inv = 1.0f / wsum;
    float weff[N_TAPS];
#pragma unroll
    for (int n = 0; n < N_TAPS; ++n) weff[n] = wn[n] * inv * tmask[n];

    // ---- Phase 2: combine (taps already in registers) ----
    float* orow = out + (size_t)row * DIM;
#pragma unroll
    for (int k = 0; k < 4; ++k) {
        float4 a = make_float4(0.f, 0.f, 0.f, 0.f);
#pragma unroll
        for (int n = 0; n < N_TAPS; ++n) {
            a.x = fmaf(weff[n], tap[k][n].x, a.x);
            a.y = fmaf(weff[n], tap[k][n].y, a.y);
            a.z = fmaf(weff[n], tap[k][n].z, a.z);
            a.w = fmaf(weff[n], tap[k][n].w, a.w);
        }
        *reinterpret_cast<float4*>(orow + k * 256 + dofs) = a;
    }
}

extern "C" void kernel_launch(void* const* d_in, const int* in_sizes, int n_in,
                              void* d_out, int out_size, void* d_ws, size_t ws_size,
                              hipStream_t stream) {
    const float* x = (const float*)d_in[0];   // [B,T,D] fp32
    const float* W = (const float*)d_in[1];   // [N_TAPS,D] fp32
    float* out = (float*)d_out;               // [B,T,D] fp32

    const int n_rows   = in_sizes[0] / DIM;          // B*T = 16384
    const int n_blocks = n_rows / ROWS_PER_BLOCK;    // 2048 (divisible by 8)

    ddrf_mixer_kernel<<<n_blocks, BLOCK_THREADS, 0, stream>>>(x, W, out, n_rows);
}